// Round 2
// baseline (945.082 us; speedup 1.0000x reference)
//
#include <hip/hip_runtime.h>
#include <stdint.h>

// HashGrid forward: instant-NGP multiresolution hash encoding.
// N=2^21 points, 16 levels x 2 features, T=2^19 entries/level, fp32.
//
// thread = n*16 + l  (one thread per point-level pair)
//   -> out offset = 2*tid (coalesced float2 stores)
//   -> 16 consecutive threads share one x[n] cache line
//
// R2 change (single-variable experiment): NON-TEMPORAL output stores.
// Theory: the 256 MB output write stream churns the 256 MB Infinity Cache
// and evicts the 64 MB table between gather reuses -> 2.1 GB HBM FETCH_SIZE
// (R1 measured). NT stores no-allocate in cache, leaving L3 to hold the
// tables. Predict FETCH 2.1 GB -> <1.2 GB, dur 688 -> 300-450 us.
//
// Correctness-critical: pos = x*scale + 0.5 as separate fp32 mul/add
// (no FMA contraction) -- floor() cell selection must match numpy.

constexpr int      kNPoints = 2097152;
constexpr int      kNLevels = 16;
constexpr uint32_t kT       = 524288u;      // 2^19
constexpr uint32_t kTMask   = kT - 1u;
constexpr uint32_t kPrimeY  = 2654435761u;  // tcnn 2D spatial-hash prime

__global__ __launch_bounds__(256) void hashgrid_fwd(
    const float* __restrict__ x,
    const float* __restrict__ table,
    float* __restrict__ out)
{
    // Per-level constants. scale = 16*1.5^l - 1 is exactly fp32-representable.
    __shared__ float    s_scale[16];
    __shared__ uint32_t s_res[16];
    if (threadIdx.x < 16) {
        const float ksc[16] = {
            15.0f, 23.0f, 35.0f, 53.0f, 80.0f, 120.5f, 181.25f, 272.375f,
            409.0625f, 614.09375f, 921.640625f, 1382.9609375f,
            2074.94140625f, 3112.912109375f, 4669.8681640625f, 7005.30224609375f};
        const uint32_t kre[16] = {16u, 24u, 36u, 54u, 81u, 122u, 183u, 274u,
                                  411u, 616u, 923u, 1384u, 2076u, 3114u, 4671u, 7007u};
        s_scale[threadIdx.x] = ksc[threadIdx.x];
        s_res[threadIdx.x]   = kre[threadIdx.x];
    }
    __syncthreads();

    const uint32_t tid = blockIdx.x * blockDim.x + threadIdx.x;
    const uint32_t l   = tid & 15u;
    const uint32_t n   = tid >> 4;

    const float2   xy    = reinterpret_cast<const float2*>(x)[n];
    const float    scale = s_scale[l];
    const uint32_t res   = s_res[l];
    const bool     dense = (l < 10u);   // res*res <= T for levels 0..9

    // pos = x*scale + 0.5, separate rounding steps (no FMA contraction)
    const float px  = __fadd_rn(__fmul_rn(xy.x, scale), 0.5f);
    const float py  = __fadd_rn(__fmul_rn(xy.y, scale), 0.5f);
    const float fpx = floorf(px);
    const float fpy = floorf(py);
    const float fx  = px - fpx;
    const float fy  = py - fpy;
    const uint32_t gx = (uint32_t)fpx;
    const uint32_t gy = (uint32_t)fpy;

    const float2* __restrict__ tab =
        reinterpret_cast<const float2*>(table) + ((size_t)l << 19);

    float ax = 0.0f, ay = 0.0f;
#pragma unroll
    for (int dx = 0; dx < 2; ++dx) {
        const uint32_t cx = gx + (uint32_t)dx;
        const float    wx = dx ? fx : (1.0f - fx);
#pragma unroll
        for (int dy = 0; dy < 2; ++dy) {
            const uint32_t cy = gy + (uint32_t)dy;
            const float    wy = dy ? fy : (1.0f - fy);
            const uint32_t idx_d = (cx + cy * res) & kTMask;
            const uint32_t idx_h = (cx ^ (cy * kPrimeY)) & kTMask;
            const uint32_t idx   = dense ? idx_d : idx_h;
            const float2   v     = tab[idx];
            const float    w     = wx * wy;
            ax = fmaf(v.x, w, ax);
            ay = fmaf(v.y, w, ay);
        }
    }

    // Non-temporal 8-B store: don't let the 256 MB write stream evict the
    // tables from the Infinity Cache.
    union { float2 f2; unsigned long long u64; } pack;
    pack.f2 = make_float2(ax, ay);
    unsigned long long* dst = reinterpret_cast<unsigned long long*>(out) + tid;
    __builtin_nontemporal_store(pack.u64, dst);
}

extern "C" void kernel_launch(void* const* d_in, const int* in_sizes, int n_in,
                              void* d_out, int out_size, void* d_ws, size_t ws_size,
                              hipStream_t stream) {
    const float* x     = (const float*)d_in[0];
    const float* table = (const float*)d_in[1];
    float*       out   = (float*)d_out;
    const int total_threads = kNPoints * kNLevels;   // 33,554,432
    hashgrid_fwd<<<total_threads / 256, 256, 0, stream>>>(x, table, out);
}

// Round 3
// 704.287 us; speedup vs baseline: 1.3419x; 1.3419x over previous
//
#include <hip/hip_runtime.h>
#include <stdint.h>

// HashGrid forward, R3: level-split kernels for L2 locality.
// R1/R2 showed FETCH_SIZE = 2.1 GB: per-wave interleaving of 16 levels makes
// every XCD's 4 MB L2 hold a ~29.5 MB hot set (hash levels 10-15 = 4 MB each,
// dense 8,9 = 1.35/3.0 MB) -> ~25% gather miss rate, LLC-traffic-bound.
// Fix: one kernel per large level (8..15): the single table fits the per-XCD
// L2 exactly (16x line reuse per XCD), output written COALESCED to a
// transposed ws slab (NT stores keep the stream from evicting the table).
// Final merge kernel: dense levels 0-7 inline (1.1 MB total -> L2-trivial),
// coalesced ws reads, LDS transpose (stride 36 -> 16B-aligned, conflict-free
// b128), coalesced float4 out.
//
// Correctness-critical: pos = x*scale + 0.5 as separate __fmul_rn/__fadd_rn
// (no FMA contraction -> floor() cell selection matches numpy). Accumulation
// order identical to R1 (passed at 4.8e-7): fmaf chain over (dx,dy) =
// (0,0),(0,1),(1,0),(1,1).

constexpr int      kNPoints = 2097152;
constexpr uint32_t kT       = 524288u;      // 2^19
constexpr uint32_t kTMask   = kT - 1u;
constexpr uint32_t kPrimeY  = 2654435761u;  // tcnn 2D spatial-hash prime

// scale = 16*1.5^l - 1, exactly fp32-representable for all 16 levels.
__device__ __host__ inline void level_consts(int l, float& sc, uint32_t& re, int& dense) {
    const float ksc[16] = {
        15.0f, 23.0f, 35.0f, 53.0f, 80.0f, 120.5f, 181.25f, 272.375f,
        409.0625f, 614.09375f, 921.640625f, 1382.9609375f,
        2074.94140625f, 3112.912109375f, 4669.8681640625f, 7005.30224609375f};
    const uint32_t kre[16] = {16u, 24u, 36u, 54u, 81u, 122u, 183u, 274u,
                              411u, 616u, 923u, 1384u, 2076u, 3114u, 4671u, 7007u};
    sc = ksc[l]; re = kre[l]; dense = (l < 10) ? 1 : 0;
}

__device__ __forceinline__ float2 encode_one(float2 xy, float scale, uint32_t res,
                                             int dense, const float2* __restrict__ tab) {
    const float px  = __fadd_rn(__fmul_rn(xy.x, scale), 0.5f);
    const float py  = __fadd_rn(__fmul_rn(xy.y, scale), 0.5f);
    const float fpx = floorf(px);
    const float fpy = floorf(py);
    const float fx  = px - fpx;
    const float fy  = py - fpy;
    const uint32_t gx = (uint32_t)fpx;
    const uint32_t gy = (uint32_t)fpy;

    float ax = 0.0f, ay = 0.0f;
#pragma unroll
    for (int dx = 0; dx < 2; ++dx) {
        const uint32_t cx = gx + (uint32_t)dx;
        const float    wx = dx ? fx : (1.0f - fx);
#pragma unroll
        for (int dy = 0; dy < 2; ++dy) {
            const uint32_t cy = gy + (uint32_t)dy;
            const float    wy = dy ? fy : (1.0f - fy);
            const uint32_t idx_d = (cx + cy * res) & kTMask;
            const uint32_t idx_h = (cx ^ (cy * kPrimeY)) & kTMask;
            const uint32_t idx   = dense ? idx_d : idx_h;
            const float2   v     = tab[idx];
            const float    w     = wx * wy;
            ax = fmaf(v.x, w, ax);
            ay = fmaf(v.y, w, ay);
        }
    }
    return make_float2(ax, ay);
}

// ---- Per-level kernel: all 2M points, ONE table (L2-resident per XCD). ----
__global__ __launch_bounds__(256) void level_kernel(
    const float* __restrict__ x,
    const float2* __restrict__ tab,   // pre-offset to level base
    float2* __restrict__ wsl,         // [N] transposed slab for this level
    float scale, uint32_t res, int dense)
{
    const uint32_t n  = blockIdx.x * 256 + threadIdx.x;
    const float2   xy = reinterpret_cast<const float2*>(x)[n];
    const float2   r  = encode_one(xy, scale, res, dense, tab);
    // NT store: don't let the ws write stream evict the table from this
    // XCD's L2 (the one place write-eviction actually bites).
    union { float2 f2; unsigned long long u64; } p; p.f2 = r;
    __builtin_nontemporal_store(p.u64, reinterpret_cast<unsigned long long*>(wsl) + n);
}

// ---- Merge kernel: dense levels [0, SPLIT) inline + ws slabs, LDS transpose. ----
template <int SPLIT>
__global__ __launch_bounds__(256) void merge_kernel(
    const float* __restrict__ x,
    const float* __restrict__ table,
    const float2* __restrict__ ws,    // [(16-SPLIT)][N]
    float* __restrict__ out)
{
    __shared__ float s[256 * 36];     // 36-float rows: 16B-aligned, bank-clean
    const uint32_t tid = threadIdx.x;
    const uint32_t n   = blockIdx.x * 256 + tid;
    const float2   xy  = reinterpret_cast<const float2*>(x)[n];

#pragma unroll
    for (int l = 0; l < SPLIT; ++l) {
        float sc; uint32_t re; int de;
        level_consts(l, sc, re, de);
        const float2* tab = reinterpret_cast<const float2*>(table) + ((size_t)l << 19);
        const float2 r = encode_one(xy, sc, re, de, tab);
        s[tid * 36 + 2 * l]     = r.x;
        s[tid * 36 + 2 * l + 1] = r.y;
    }
#pragma unroll
    for (int j = 0; j < 16 - SPLIT; ++j) {
        const float2 v = ws[(size_t)j * kNPoints + n];   // coalesced
        s[tid * 36 + 2 * (SPLIT + j)]     = v.x;
        s[tid * 36 + 2 * (SPLIT + j) + 1] = v.y;
    }
    __syncthreads();

    float4* outb = reinterpret_cast<float4*>(out + (size_t)blockIdx.x * 8192);
#pragma unroll
    for (int k = 0; k < 8; ++k) {
        const uint32_t q   = tid + k * 256;      // float4 index in block tile
        const uint32_t row = q >> 3;             // point within block
        const uint32_t c   = (q & 7u) * 4u;      // column (floats)
        const float* sp = &s[row * 36 + c];
        outb[q] = make_float4(sp[0], sp[1], sp[2], sp[3]);  // coalesced
    }
}

// ---- Fallback: R1 single kernel (passed at 688 us) if ws is too small. ----
__global__ __launch_bounds__(256) void hashgrid_fwd_fallback(
    const float* __restrict__ x,
    const float* __restrict__ table,
    float* __restrict__ out)
{
    const uint32_t tid = blockIdx.x * blockDim.x + threadIdx.x;
    const uint32_t l   = tid & 15u;
    const uint32_t n   = tid >> 4;
    float sc; uint32_t re; int de;
    level_consts((int)l, sc, re, de);
    const float2 xy = reinterpret_cast<const float2*>(x)[n];
    const float2* tab = reinterpret_cast<const float2*>(table) + ((size_t)l << 19);
    const float2 r = encode_one(xy, sc, re, de, tab);
    reinterpret_cast<float2*>(out)[tid] = r;
}

extern "C" void kernel_launch(void* const* d_in, const int* in_sizes, int n_in,
                              void* d_out, int out_size, void* d_ws, size_t ws_size,
                              hipStream_t stream) {
    const float* x     = (const float*)d_in[0];
    const float* table = (const float*)d_in[1];
    float*       out   = (float*)d_out;
    const int nblk = kNPoints / 256;   // 8192

    const size_t need8 = (size_t)8 * kNPoints * sizeof(float2);  // 128 MB (levels 8..15)
    const size_t need6 = (size_t)6 * kNPoints * sizeof(float2);  //  96 MB (levels 10..15)

    if (ws_size >= need8) {
        float2* ws = (float2*)d_ws;
        for (int l = 8; l < 16; ++l) {
            float sc; uint32_t re; int de;
            level_consts(l, sc, re, de);
            level_kernel<<<nblk, 256, 0, stream>>>(
                x, reinterpret_cast<const float2*>(table) + ((size_t)l << 19),
                ws + (size_t)(l - 8) * kNPoints, sc, re, de);
        }
        merge_kernel<8><<<nblk, 256, 0, stream>>>(x, table, ws, out);
    } else if (ws_size >= need6) {
        float2* ws = (float2*)d_ws;
        for (int l = 10; l < 16; ++l) {
            float sc; uint32_t re; int de;
            level_consts(l, sc, re, de);
            level_kernel<<<nblk, 256, 0, stream>>>(
                x, reinterpret_cast<const float2*>(table) + ((size_t)l << 19),
                ws + (size_t)(l - 10) * kNPoints, sc, re, de);
        }
        merge_kernel<10><<<nblk, 256, 0, stream>>>(x, table, ws, out);
    } else {
        hashgrid_fwd_fallback<<<(kNPoints * 16) / 256, 256, 0, stream>>>(x, table, out);
    }
}